// Round 11
// baseline (243.065 us; speedup 1.0000x reference)
//
#include <hip/hip_runtime.h>
#include <hip/hip_bf16.h>
#include <math.h>

#define B 32
#define N 8400
#define M 60
#define C 80
#define KMAX 13
#define INF_COST 1e8f
#define WSLICE 2100   // N/4, one contiguous slice per wave

// ---------- iou: bit-exact IEEE (feeds dynamic_ks sum + metric output) ----------
__device__ __forceinline__ float iou_fn(
    float px1, float py1, float px2, float py2,
    float gx1, float gy1, float gx2, float gy2)
{
#pragma clang fp contract(off)
    float ltx = fmaxf(px1, gx1), lty = fmaxf(py1, gy1);
    float rbx = fminf(px2, gx2), rby = fminf(py2, gy2);
    float wx = fmaxf(rbx - ltx, 0.0f), wy = fmaxf(rby - lty, 0.0f);
    float inter = wx * wy;
    float a1 = (px2 - px1) * (py2 - py1);
    float a2 = (gx2 - gx1) * (gy2 - gy1);
    float uni = fmaxf(a1 + a2 - inter, 1e-6f);
    return inter / uni;
}

// ---------- cost: fast hardware transcendentals (single producer of cost bits) ----------
__device__ __forceinline__ float cost_fast(
    float iou, float logit,
    float pcx, float pcy, float rstride,   // rstride = 1/stride (exact: pow2)
    float gcx, float gcy)
{
    const float LOG2_10 = 3.3219280948873623f;
    const float LOG2_E  = 1.4426950408889634f;
    const float LN_2    = 0.6931471805599453f;
    float dx = pcx - gcx, dy = pcy - gcy;
    float dist = __builtin_amdgcn_sqrtf(dx * dx + dy * dy) * rstride;
    float soft = __builtin_amdgcn_exp2f((dist - 3.0f) * LOG2_10);
    float iouc = __builtin_amdgcn_logf(iou + 1e-7f) * (-3.0f * LN_2);
    float e    = __builtin_amdgcn_exp2f(-logit * LOG2_E);
    float sig  = __builtin_amdgcn_rcpf(1.0f + e);
    float t    = __builtin_amdgcn_exp2f(-fabsf(logit) * LOG2_E);
    float sp   = __builtin_amdgcn_logf(1.0f + t) * LN_2;
    float bce  = fmaxf(logit, 0.0f) - logit * iou + sp;
    float scale = iou - sig;
    float cls  = bce * scale * scale;
    return (cls + iouc) + soft;
}

// ---------- kernel 1: valid_mask[b,n] ----------
__global__ __launch_bounds__(256) void k_valid(
    const float* __restrict__ priors,
    const float* __restrict__ gt_bboxes,
    const float* __restrict__ pad,
    unsigned char* __restrict__ valid)
{
    int idx = blockIdx.x * 256 + threadIdx.x;
    if (idx >= B * N) return;
    int b = idx / N, n = idx % N;
    float px = priors[n * 4 + 0];
    float py = priors[n * 4 + 1];
    const float* g = gt_bboxes + (size_t)b * M * 4;
    const float* pf = pad + (size_t)b * M;
    unsigned char v = 0;
    for (int m = 0; m < M; m++) {
        float x1 = g[m * 4 + 0], y1 = g[m * 4 + 1];
        float x2 = g[m * 4 + 2], y2 = g[m * 4 + 3];
        float mn = fminf(fminf(px - x1, py - y1), fminf(x2 - px, y2 - py));
        if (mn > 0.0f && pf[m] > 0.0f) { v = 1; break; }
    }
    valid[idx] = v;
}

// ---------- kernel 1b: transpose + COST: t[b][m][n] = cost(b,n,m) ----------
__global__ __launch_bounds__(256) void k_cost(
    const float* __restrict__ scores,
    const int*   __restrict__ labels,
    const float* __restrict__ pred_bboxes,
    const float* __restrict__ priors,
    const float* __restrict__ gt_bboxes,
    const unsigned char* __restrict__ valid,
    float* __restrict__ t)
{
    __shared__ float s_t[80][65];
    __shared__ float s_g[M][6];
    __shared__ int   s_lab[M];

    const int cidx = blockIdx.x;
    const int b = cidx / 132;
    const int tile = cidx % 132;
    const int n0 = tile * 64;
    const int lim = (N - n0 < 64) ? (N - n0) : 64;

    if (threadIdx.x < M) {
        int m = threadIdx.x, gi = b * M + m;
        float4 g = ((const float4*)gt_bboxes)[gi];
        s_g[m][0] = g.x; s_g[m][1] = g.y; s_g[m][2] = g.z; s_g[m][3] = g.w;
        s_g[m][4] = (g.x + g.z) * 0.5f;
        s_g[m][5] = (g.y + g.w) * 0.5f;
        s_lab[m] = labels[gi];
    }

    const float4* src4 = (const float4*)(scores + ((size_t)b * N + n0) * C);
    for (int idx = threadIdx.x; idx < lim * 20; idx += 256) {
        int r = idx / 20, qq = idx % 20;
        float4 v = src4[r * 20 + qq];
        s_t[4 * qq + 0][r] = v.x;
        s_t[4 * qq + 1][r] = v.y;
        s_t[4 * qq + 2][r] = v.z;
        s_t[4 * qq + 3][r] = v.w;
    }
    __syncthreads();

    const int q = threadIdx.x & 15;
    if (4 * q >= lim) return;

    const size_t nb = (size_t)b * N + n0 + 4 * q;
    const unsigned char* vr = valid + nb;
    bool V0 = vr[0], V1 = vr[1], V2 = vr[2], V3 = vr[3];
    float* trow = t + (size_t)b * M * N + n0 + 4 * q;

    if (!(V0 | V1 | V2 | V3)) {
        float4 o = make_float4(INF_COST, INF_COST, INF_COST, INF_COST);
        for (int m = threadIdx.x >> 4; m < M; m += 16)
            *(float4*)(trow + (size_t)m * N) = o;
        return;
    }

    const float4* pbx = (const float4*)pred_bboxes;
    const float4* prx = (const float4*)priors;
    float4 P0 = pbx[nb + 0], P1 = pbx[nb + 1], P2 = pbx[nb + 2], P3 = pbx[nb + 3];
    float4 R0 = prx[n0 + 4 * q + 0], R1 = prx[n0 + 4 * q + 1];
    float4 R2 = prx[n0 + 4 * q + 2], R3 = prx[n0 + 4 * q + 3];
    float rs0 = __builtin_amdgcn_rcpf(R0.z);
    float rs1 = __builtin_amdgcn_rcpf(R1.z);
    float rs2 = __builtin_amdgcn_rcpf(R2.z);
    float rs3 = __builtin_amdgcn_rcpf(R3.z);

    for (int m = threadIdx.x >> 4; m < M; m += 16) {
        float gx1 = s_g[m][0], gy1 = s_g[m][1], gx2 = s_g[m][2], gy2 = s_g[m][3];
        float gcx = s_g[m][4], gcy = s_g[m][5];
        int lab = s_lab[m];
        float4 o;
        o.x = V0 ? cost_fast(iou_fn(P0.x, P0.y, P0.z, P0.w, gx1, gy1, gx2, gy2),
                             s_t[lab][4 * q + 0], R0.x, R0.y, rs0, gcx, gcy) : INF_COST;
        o.y = V1 ? cost_fast(iou_fn(P1.x, P1.y, P1.z, P1.w, gx1, gy1, gx2, gy2),
                             s_t[lab][4 * q + 1], R1.x, R1.y, rs1, gcx, gcy) : INF_COST;
        o.z = V2 ? cost_fast(iou_fn(P2.x, P2.y, P2.z, P2.w, gx1, gy1, gx2, gy2),
                             s_t[lab][4 * q + 2], R2.x, R2.y, rs2, gcx, gcy) : INF_COST;
        o.w = V3 ? cost_fast(iou_fn(P3.x, P3.y, P3.z, P3.w, gx1, gy1, gx2, gy2),
                             s_t[lab][4 * q + 3], R3.x, R3.y, rs3, gcx, gcy) : INF_COST;
        *(float4*)(trow + (size_t)m * N) = o;
    }
}

// ---------- kernel 2: register-list selection (cost preloaded; zero-skip iou) ----------
__global__ __launch_bounds__(256) void k_select(
    const float* __restrict__ pred_bboxes,
    const float* __restrict__ pred_scores,
    const float* __restrict__ tsc,
    const float* __restrict__ priors,
    const int*   __restrict__ gt_labels,
    const float* __restrict__ gt_bboxes,
    const float* __restrict__ pad,
    const unsigned char* __restrict__ valid,
    float* __restrict__ cK, int* __restrict__ nK,
    int use_t)
{
    __shared__ float s_tv[4][KMAX];     // per-wave top-13 iou (descending, >0 only)
    __shared__ float s_bv[4][KMAX];     // per-wave bottom-13 cost (ascending lex)
    __shared__ int   s_bn[4][KMAX];

    const int bm = blockIdx.x;
    if (pad[bm] == 0.0f) return;        // padded GT: cK/nK never consumed

    const int b = bm / M;
    const int tid = threadIdx.x;
    const int lane = tid & 63;
    const int w = tid >> 6;
    const int base = w * WSLICE;
    const int end = base + WSLICE;

    const float4 g = ((const float4*)gt_bboxes)[bm];
    const float gx1 = g.x, gy1 = g.y, gx2 = g.z, gy2 = g.w;
    const float gcx = (gx1 + gx2) * 0.5f, gcy = (gy1 + gy2) * 0.5f;
    const int label = gt_labels[bm];
    const float4* pb4 = ((const float4*)pred_bboxes) + (size_t)b * N;
    const float* tcol = tsc + (size_t)bm * N;
    const float* srow = pred_scores + (size_t)b * N * C;
    const unsigned char* vrow = valid + (size_t)b * N;
    const float4* pr4 = (const float4*)priors;

    float t13[KMAX];
    float cv[KMAX]; int cn[KMAX];
#pragma unroll
    for (int j = 0; j < KMAX; ++j) {
        t13[j] = -1.0f;
        cv[j] = INFINITY; cn[j] = 0x7fffffff;
    }

    // ---- fused pass: iou (compute) + cost (load) ----
#pragma unroll 2
    for (int n = base + lane; n < end; n += 64) {
        float4 p = pb4[n];
        float v = iou_fn(p.x, p.y, p.z, p.w, gx1, gy1, gx2, gy2);

        // zero-skip insert: zeros add 0.0 to the sum bitwise, so only positives kept
        if (v > 0.0f && v > t13[KMAX - 1]) {
#pragma unroll
            for (int j = KMAX - 1; j >= 1; --j)
                t13[j] = (t13[j] >= v) ? t13[j] : (t13[j - 1] >= v ? v : t13[j - 1]);
            t13[0] = (t13[0] >= v) ? t13[0] : v;
        }

        float c;
        if (use_t) {
            c = tcol[n];
        } else {
            if (vrow[n]) {
                float4 pr = pr4[n];
                c = cost_fast(v, srow[(size_t)n * C + label], pr.x, pr.y,
                              __builtin_amdgcn_rcpf(pr.z), gcx, gcy);
            } else c = INF_COST;
        }
        bool rej = (cv[KMAX - 1] < c) || (cv[KMAX - 1] == c && cn[KMAX - 1] < n);
        if (!rej) {
#pragma unroll
            for (int j = KMAX - 1; j >= 1; --j) {
                bool keep  = (cv[j] < c)     || (cv[j] == c     && cn[j] < n);
                bool pkeep = (cv[j - 1] < c) || (cv[j - 1] == c && cn[j - 1] < n);
                float nv = keep ? cv[j] : (pkeep ? c : cv[j - 1]);
                int   nn = keep ? cn[j] : (pkeep ? n : cn[j - 1]);
                cv[j] = nv; cn[j] = nn;
            }
            bool keep0 = (cv[0] < c) || (cv[0] == c && cn[0] < n);
            if (!keep0) { cv[0] = c; cn[0] = n; }
        }
    }

    // ---- 13 wave pops: max iou over heads (ties value-identical; lane tie-break) ----
    for (int r = 0; r < KMAX; ++r) {
        float bv = t13[0]; int bl = lane;
#pragma unroll
        for (int d = 1; d < 64; d <<= 1) {
            float ov = __shfl_xor(bv, d);
            int   ol = __shfl_xor(bl, d);
            if (ov > bv || (ov == bv && ol < bl)) { bv = ov; bl = ol; }
        }
        if (lane == 0) s_tv[w][r] = bv;
        if (lane == bl) {
#pragma unroll
            for (int j = 0; j < KMAX - 1; ++j) t13[j] = t13[j + 1];
            t13[KMAX - 1] = -1.0f;
        }
    }

    // ---- 13 wave pops: lex-min (cost, n); winner lane = (n - base) & 63 ----
    for (int r = 0; r < KMAX; ++r) {
        float bv = cv[0]; int bn = cn[0];
#pragma unroll
        for (int d = 1; d < 64; d <<= 1) {
            float ov = __shfl_xor(bv, d);
            int   on = __shfl_xor(bn, d);
            if (ov < bv || (ov == bv && on < bn)) { bv = ov; bn = on; }
        }
        if (lane == 0) { s_bv[w][r] = bv; s_bn[w][r] = bn; }
        if (lane == ((bn - base) & 63)) {
#pragma unroll
            for (int j = 0; j < KMAX - 1; ++j) { cv[j] = cv[j + 1]; cn[j] = cn[j + 1]; }
            cv[KMAX - 1] = INFINITY; cn[KMAX - 1] = 0x7fffffff;
        }
    }

    __syncthreads();   // the ONLY block barrier

    if (tid == 0) {
        // merge descending top-13 (positives); sentinels <=0 mark exhaustion
        int p0 = 0, p1 = 0, p2 = 0, p3 = 0;
        float ss = 0.0f;
        for (int r = 0; r < KMAX; ++r) {
            float v0 = s_tv[0][p0], v1 = s_tv[1][p1], v2 = s_tv[2][p2], v3 = s_tv[3][p3];
            float bv = v0; int bw = 0;
            if (v1 > bv) { bv = v1; bw = 1; }
            if (v2 > bv) { bv = v2; bw = 2; }
            if (v3 > bv) { bv = v3; bw = 3; }
            if (bv <= 0.0f) break;              // remaining top-k entries are zeros: +0.0 is a no-op
            ss += bv;                           // descending-order sum == top_k().sum()
            if (bw == 0) p0++; else if (bw == 1) p1++; else if (bw == 2) p2++; else p3++;
        }
        int K = (int)ss;                        // trunc == astype(int32)
        if (K < 1) K = 1;

        // merge ascending (cost, n) lex; K-th element is the threshold pair
        int q0 = 0, q1 = 0, q2 = 0, q3 = 0;
        float ck = 0.0f; int nk = 0;
        for (int r = 0; r < K; ++r) {
            float bv = s_bv[0][q0]; int bn = s_bn[0][q0]; int bw = 0;
            float v; int nn;
            v = s_bv[1][q1]; nn = s_bn[1][q1];
            if (v < bv || (v == bv && nn < bn)) { bv = v; bn = nn; bw = 1; }
            v = s_bv[2][q2]; nn = s_bn[2][q2];
            if (v < bv || (v == bv && nn < bn)) { bv = v; bn = nn; bw = 2; }
            v = s_bv[3][q3]; nn = s_bn[3][q3];
            if (v < bv || (v == bv && nn < bn)) { bv = v; bn = nn; bw = 3; }
            ck = bv; nk = bn;
            if (bw == 0) q0++; else if (bw == 1) q1++; else if (bw == 2) q2++; else q3++;
        }
        cK[bm] = ck; nK[bm] = nk;
    }
}

// ---------- kernel 3: per-(b,n) row ----------
__global__ __launch_bounds__(256) void k_assign(
    const float* __restrict__ pred_bboxes,
    const float* __restrict__ pred_scores,
    const float* __restrict__ tsc,
    const float* __restrict__ priors,
    const int*   __restrict__ gt_labels,
    const float* __restrict__ gt_bboxes,
    const float* __restrict__ pad,
    const unsigned char* __restrict__ valid,
    const float* __restrict__ cK,
    const int*   __restrict__ nK,
    float* __restrict__ out,
    int use_t)
{
    __shared__ float s_box[M][4];
    __shared__ float s_gc[M][2];
    __shared__ float s_ck[M];
    __shared__ int   s_lab[M];
    __shared__ int   s_nk[M];
    __shared__ unsigned char s_gtv[M];

    const int cidx = blockIdx.x;
    const int b = cidx / 33;
    const int chunk = cidx % 33;
    const int n = chunk * 256 + threadIdx.x;

    if (threadIdx.x < M) {
        int m = threadIdx.x, gi = b * M + m;
        float4 g = ((const float4*)gt_bboxes)[gi];
        s_box[m][0] = g.x; s_box[m][1] = g.y; s_box[m][2] = g.z; s_box[m][3] = g.w;
        s_gc[m][0] = (g.x + g.z) * 0.5f;
        s_gc[m][1] = (g.y + g.w) * 0.5f;
        s_ck[m] = cK[gi];
        s_lab[m] = gt_labels[gi];
        s_nk[m] = nK[gi];
        s_gtv[m] = (pad[gi] > 0.0f) ? 1 : 0;
    }
    __syncthreads();
    if (n >= N) return;

    const size_t idx = (size_t)b * N + n;

    int count = 0, firstm = -1;
    float minc = INFINITY; int amin = 0;
    float firstiou = 0.0f, aminiou = 0.0f;

    if (use_t) {
        const float* tb = tsc + (size_t)b * M * N;
#pragma unroll 4
        for (int m = 0; m < M; m++) {
            float c = tb[(size_t)m * N + n];
            if (c < minc) { minc = c; amin = m; }
            float ckm = s_ck[m]; int nkm = s_nk[m];
            bool matched = s_gtv[m] && (c < ckm || (c == ckm && n <= nkm));
            if (matched) { count++; if (firstm < 0) firstm = m; }
        }
        int mstar = (count > 1) ? amin : firstm;
        float mi = 0.0f;
        if (mstar >= 0) {
            float4 p = ((const float4*)pred_bboxes)[idx];
            mi = iou_fn(p.x, p.y, p.z, p.w,
                        s_box[mstar][0], s_box[mstar][1], s_box[mstar][2], s_box[mstar][3]);
        }
        float* o_lab = out;
        float* o_w   = out + (size_t)B * N;
        float* o_box = out + (size_t)2 * B * N;
        float* o_met = out + (size_t)6 * B * N;
        o_w[idx] = 1.0f;
        if (mstar >= 0) {
            o_lab[idx] = (float)s_lab[mstar];
            o_box[idx * 4 + 0] = s_box[mstar][0];
            o_box[idx * 4 + 1] = s_box[mstar][1];
            o_box[idx * 4 + 2] = s_box[mstar][2];
            o_box[idx * 4 + 3] = s_box[mstar][3];
            o_met[idx] = mi;
        } else {
            o_lab[idx] = (float)C;
            o_box[idx * 4 + 0] = 0.0f;
            o_box[idx * 4 + 1] = 0.0f;
            o_box[idx * 4 + 2] = 0.0f;
            o_box[idx * 4 + 3] = 0.0f;
            o_met[idx] = 0.0f;
        }
        return;
    }

    // -------- fallback (use_t == 0) --------
    const float4 p = ((const float4*)pred_bboxes)[idx];
    const float4 pr = ((const float4*)priors)[n];
    const float rst = __builtin_amdgcn_rcpf(pr.z);
    const int vn = valid[idx];
    const float* scores = pred_scores + idx * C;

    for (int m = 0; m < M; m++) {
        float iou = iou_fn(p.x, p.y, p.z, p.w,
                           s_box[m][0], s_box[m][1], s_box[m][2], s_box[m][3]);
        float c;
        if (vn) {
            float logit = scores[s_lab[m]];
            c = cost_fast(iou, logit, pr.x, pr.y, rst, s_gc[m][0], s_gc[m][1]);
        } else {
            c = INF_COST;
        }
        if (c < minc) { minc = c; amin = m; aminiou = iou; }
        float ckm = s_ck[m]; int nkm = s_nk[m];
        bool matched = s_gtv[m] && (c < ckm || (c == ckm && n <= nkm));
        if (matched) { count++; if (firstm < 0) { firstm = m; firstiou = iou; } }
    }

    int mstar; float mi;
    if (count > 1)       { mstar = amin;   mi = aminiou; }
    else if (count == 1) { mstar = firstm; mi = firstiou; }
    else                 { mstar = -1;     mi = 0.0f; }

    float* o_lab = out;
    float* o_w   = out + (size_t)B * N;
    float* o_box = out + (size_t)2 * B * N;
    float* o_met = out + (size_t)6 * B * N;
    o_w[idx] = 1.0f;
    if (mstar >= 0) {
        o_lab[idx] = (float)s_lab[mstar];
        o_box[idx * 4 + 0] = s_box[mstar][0];
        o_box[idx * 4 + 1] = s_box[mstar][1];
        o_box[idx * 4 + 2] = s_box[mstar][2];
        o_box[idx * 4 + 3] = s_box[mstar][3];
        o_met[idx] = mi;
    } else {
        o_lab[idx] = (float)C;
        o_box[idx * 4 + 0] = 0.0f;
        o_box[idx * 4 + 1] = 0.0f;
        o_box[idx * 4 + 2] = 0.0f;
        o_box[idx * 4 + 3] = 0.0f;
        o_met[idx] = 0.0f;
    }
}

extern "C" void kernel_launch(void* const* d_in, const int* in_sizes, int n_in,
                              void* d_out, int out_size, void* d_ws, size_t ws_size,
                              hipStream_t stream) {
    const float* pred_bboxes = (const float*)d_in[0];
    const float* pred_scores = (const float*)d_in[1];
    const float* priors      = (const float*)d_in[2];
    const int*   gt_labels   = (const int*)d_in[3];
    const float* gt_bboxes   = (const float*)d_in[4];
    const float* pad         = (const float*)d_in[5];
    float* out = (float*)d_out;

    const size_t t_bytes = (size_t)B * M * N * sizeof(float);
    const size_t need = t_bytes + (size_t)B * N + (size_t)B * M * 8;
    const int use_t = (ws_size >= need) ? 1 : 0;

    unsigned char* ws = (unsigned char*)d_ws;
    float* tsc; unsigned char* valid; float* cKp; int* nKp;
    if (use_t) {
        tsc   = (float*)ws;
        valid = ws + t_bytes;
        cKp   = (float*)(ws + t_bytes + (size_t)B * N);
        nKp   = (int*)  (ws + t_bytes + (size_t)B * N + (size_t)B * M * 4);
    } else {
        tsc   = (float*)ws;   // never dereferenced
        valid = ws;
        cKp   = (float*)(ws + (size_t)B * N);
        nKp   = (int*)  (ws + (size_t)B * N + (size_t)B * M * 4);
    }

    k_valid<<<(B * N + 255) / 256, 256, 0, stream>>>(priors, gt_bboxes, pad, valid);
    if (use_t)
        k_cost<<<B * 132, 256, 0, stream>>>(pred_scores, gt_labels, pred_bboxes, priors,
                                            gt_bboxes, valid, tsc);
    k_select<<<B * M, 256, 0, stream>>>(pred_bboxes, pred_scores, tsc, priors, gt_labels,
                                        gt_bboxes, pad, valid, cKp, nKp, use_t);
    k_assign<<<33 * B, 256, 0, stream>>>(pred_bboxes, pred_scores, tsc, priors, gt_labels,
                                         gt_bboxes, pad, valid, cKp, nKp, out, use_t);
}

// Round 12
// 177.778 us; speedup vs baseline: 1.3672x; 1.3672x over previous
//
#include <hip/hip_runtime.h>
#include <hip/hip_bf16.h>
#include <math.h>

#define B 32
#define N 8400
#define M 60
#define C 80
#define KMAX 13
#define INF_COST 1e8f
#define NJ 33   // ceil(N/256)
#define NH 8    // histogram copies

// ---------- iou: bit-exact IEEE (feeds dynamic_ks sum + metric output) ----------
__device__ __forceinline__ float iou_fn(
    float px1, float py1, float px2, float py2,
    float gx1, float gy1, float gx2, float gy2)
{
#pragma clang fp contract(off)
    float ltx = fmaxf(px1, gx1), lty = fmaxf(py1, gy1);
    float rbx = fminf(px2, gx2), rby = fminf(py2, gy2);
    float wx = fmaxf(rbx - ltx, 0.0f), wy = fmaxf(rby - lty, 0.0f);
    float inter = wx * wy;
    float a1 = (px2 - px1) * (py2 - py1);
    float a2 = (gx2 - gx1) * (gy2 - gy1);
    float uni = fmaxf(a1 + a2 - inter, 1e-6f);
    return inter / uni;
}

// ---------- cost: fast hardware transcendentals (single producer of cost bits) ----------
__device__ __forceinline__ float cost_fast(
    float iou, float logit,
    float pcx, float pcy, float rstride,   // rstride = 1/stride (exact: pow2)
    float gcx, float gcy)
{
    const float LOG2_10 = 3.3219280948873623f;
    const float LOG2_E  = 1.4426950408889634f;
    const float LN_2    = 0.6931471805599453f;
    float dx = pcx - gcx, dy = pcy - gcy;
    float dist = __builtin_amdgcn_sqrtf(dx * dx + dy * dy) * rstride;
    float soft = __builtin_amdgcn_exp2f((dist - 3.0f) * LOG2_10);
    float iouc = __builtin_amdgcn_logf(iou + 1e-7f) * (-3.0f * LN_2);
    float e    = __builtin_amdgcn_exp2f(-logit * LOG2_E);
    float sig  = __builtin_amdgcn_rcpf(1.0f + e);
    float t    = __builtin_amdgcn_exp2f(-fabsf(logit) * LOG2_E);
    float sp   = __builtin_amdgcn_logf(1.0f + t) * LN_2;
    float bce  = fmaxf(logit, 0.0f) - logit * iou + sp;
    float scale = iou - sig;
    float cls  = bce * scale * scale;
    return (cls + iouc) + soft;
}

// ---------- kernel 1: valid_mask[b,n] ----------
__global__ __launch_bounds__(256) void k_valid(
    const float* __restrict__ priors,
    const float* __restrict__ gt_bboxes,
    const float* __restrict__ pad,
    unsigned char* __restrict__ valid)
{
    int idx = blockIdx.x * 256 + threadIdx.x;
    if (idx >= B * N) return;
    int b = idx / N, n = idx % N;
    float px = priors[n * 4 + 0];
    float py = priors[n * 4 + 1];
    const float* g = gt_bboxes + (size_t)b * M * 4;
    const float* pf = pad + (size_t)b * M;
    unsigned char v = 0;
    for (int m = 0; m < M; m++) {
        float x1 = g[m * 4 + 0], y1 = g[m * 4 + 1];
        float x2 = g[m * 4 + 2], y2 = g[m * 4 + 3];
        float mn = fminf(fminf(px - x1, py - y1), fminf(x2 - px, y2 - py));
        if (mn > 0.0f && pf[m] > 0.0f) { v = 1; break; }
    }
    valid[idx] = v;
}

// ---------- kernel 1b: transpose + COST: t[b][m][n] = cost(b,n,m) ----------
__global__ __launch_bounds__(256) void k_cost(
    const float* __restrict__ scores,
    const int*   __restrict__ labels,
    const float* __restrict__ pred_bboxes,
    const float* __restrict__ priors,
    const float* __restrict__ gt_bboxes,
    const unsigned char* __restrict__ valid,
    float* __restrict__ t)
{
    __shared__ float s_t[80][65];
    __shared__ float s_g[M][6];
    __shared__ int   s_lab[M];

    const int cidx = blockIdx.x;
    const int b = cidx / 132;
    const int tile = cidx % 132;
    const int n0 = tile * 64;
    const int lim = (N - n0 < 64) ? (N - n0) : 64;

    if (threadIdx.x < M) {
        int m = threadIdx.x, gi = b * M + m;
        float4 g = ((const float4*)gt_bboxes)[gi];
        s_g[m][0] = g.x; s_g[m][1] = g.y; s_g[m][2] = g.z; s_g[m][3] = g.w;
        s_g[m][4] = (g.x + g.z) * 0.5f;
        s_g[m][5] = (g.y + g.w) * 0.5f;
        s_lab[m] = labels[gi];
    }

    const float4* src4 = (const float4*)(scores + ((size_t)b * N + n0) * C);
    for (int idx = threadIdx.x; idx < lim * 20; idx += 256) {
        int r = idx / 20, qq = idx % 20;
        float4 v = src4[r * 20 + qq];
        s_t[4 * qq + 0][r] = v.x;
        s_t[4 * qq + 1][r] = v.y;
        s_t[4 * qq + 2][r] = v.z;
        s_t[4 * qq + 3][r] = v.w;
    }
    __syncthreads();

    const int q = threadIdx.x & 15;
    if (4 * q >= lim) return;

    const size_t nb = (size_t)b * N + n0 + 4 * q;
    const unsigned char* vr = valid + nb;
    bool V0 = vr[0], V1 = vr[1], V2 = vr[2], V3 = vr[3];
    float* trow = t + (size_t)b * M * N + n0 + 4 * q;

    if (!(V0 | V1 | V2 | V3)) {
        float4 o = make_float4(INF_COST, INF_COST, INF_COST, INF_COST);
        for (int m = threadIdx.x >> 4; m < M; m += 16)
            *(float4*)(trow + (size_t)m * N) = o;
        return;
    }

    const float4* pbx = (const float4*)pred_bboxes;
    const float4* prx = (const float4*)priors;
    float4 P0 = pbx[nb + 0], P1 = pbx[nb + 1], P2 = pbx[nb + 2], P3 = pbx[nb + 3];
    float4 R0 = prx[n0 + 4 * q + 0], R1 = prx[n0 + 4 * q + 1];
    float4 R2 = prx[n0 + 4 * q + 2], R3 = prx[n0 + 4 * q + 3];
    float rs0 = __builtin_amdgcn_rcpf(R0.z);
    float rs1 = __builtin_amdgcn_rcpf(R1.z);
    float rs2 = __builtin_amdgcn_rcpf(R2.z);
    float rs3 = __builtin_amdgcn_rcpf(R3.z);

    for (int m = threadIdx.x >> 4; m < M; m += 16) {
        float gx1 = s_g[m][0], gy1 = s_g[m][1], gx2 = s_g[m][2], gy2 = s_g[m][3];
        float gcx = s_g[m][4], gcy = s_g[m][5];
        int lab = s_lab[m];
        float4 o;
        o.x = V0 ? cost_fast(iou_fn(P0.x, P0.y, P0.z, P0.w, gx1, gy1, gx2, gy2),
                             s_t[lab][4 * q + 0], R0.x, R0.y, rs0, gcx, gcy) : INF_COST;
        o.y = V1 ? cost_fast(iou_fn(P1.x, P1.y, P1.z, P1.w, gx1, gy1, gx2, gy2),
                             s_t[lab][4 * q + 1], R1.x, R1.y, rs1, gcx, gcy) : INF_COST;
        o.z = V2 ? cost_fast(iou_fn(P2.x, P2.y, P2.z, P2.w, gx1, gy1, gx2, gy2),
                             s_t[lab][4 * q + 2], R2.x, R2.y, rs2, gcx, gcy) : INF_COST;
        o.w = V3 ? cost_fast(iou_fn(P3.x, P3.y, P3.z, P3.w, gx1, gy1, gx2, gy2),
                             s_t[lab][4 * q + 3], R3.x, R3.y, rs3, gcx, gcy) : INF_COST;
        *(float4*)(trow + (size_t)m * N) = o;
    }
}

// ---------- radix helpers ----------
__device__ __forceinline__ void hist_zero(unsigned (*s_h)[257], int tid) {
    unsigned* f = &s_h[0][0];
    for (int j = tid; j < NH * 257; j += 256) f[j] = 0;
}

__device__ __forceinline__ void hist_pick(unsigned (*s_h)[257], unsigned* s_wsum,
    unsigned* s_sel, int tid, int lane, int w, unsigned need, int infbin, unsigned infcnt)
{
    unsigned cnt = 0;
#pragma unroll
    for (int c = 0; c < NH; ++c) cnt += s_h[c][tid];
    if (tid == infbin) cnt += infcnt;
    unsigned x = cnt;
#pragma unroll
    for (int d = 1; d < 64; d <<= 1) {
        unsigned y = (unsigned)__shfl_up((int)x, d);
        if (lane >= d) x += y;
    }
    if (lane == 63) s_wsum[w] = x;
    __syncthreads();
    unsigned off = 0;
    for (int ww = 0; ww < w; ++ww) off += s_wsum[ww];
    unsigned incl = x + off;
    unsigned excl = incl - cnt;
    if (tid == 255) s_sel[2] = incl;
    if (need != 0u && excl < need && need <= incl) { s_sel[0] = (unsigned)tid; s_sel[1] = excl; }
    __syncthreads();
}

// ---------- kernel 2: radix selection, register-resident, no big LDS ----------
__global__ __launch_bounds__(256) void k_select(
    const float* __restrict__ pred_bboxes,
    const float* __restrict__ pred_scores,
    const float* __restrict__ tsc,
    const float* __restrict__ priors,
    const int*   __restrict__ gt_labels,
    const float* __restrict__ gt_bboxes,
    const float* __restrict__ pad,
    const unsigned char* __restrict__ valid,
    float* __restrict__ cK, int* __restrict__ nK,
    int use_t)
{
    __shared__ unsigned s_h[NH][257];    // 8.2 KB bank-spread histogram copies
    __shared__ unsigned s_wsum[4];
    __shared__ unsigned s_sel[4];
    __shared__ unsigned s_wjc[4][NJ];    // per-wave per-j tie counts (528 B)
    __shared__ float    s_coll[16];
    __shared__ unsigned s_cnt;
    __shared__ unsigned s_infcnt;

    const int bm = blockIdx.x;
    if (pad[bm] == 0.0f) return;         // padded GT: cK/nK never consumed

    const int b = bm / M;
    const int tid = threadIdx.x;
    const int lane = tid & 63;
    const int w = tid >> 6;

    const float4 g = ((const float4*)gt_bboxes)[bm];
    const float gx1 = g.x, gy1 = g.y, gx2 = g.z, gy2 = g.w;
    const float gcx = (gx1 + gx2) * 0.5f, gcy = (gy1 + gy2) * 0.5f;
    const int label = gt_labels[bm];
    const float4* pb4 = ((const float4*)pred_bboxes) + (size_t)b * N;

    float myv[NJ];

    // ======== pass A: iou into registers + level-0 histogram (positives only) ========
    hist_zero(s_h, tid);
    if (tid == 0) s_cnt = 0;
    __syncthreads();
#pragma unroll
    for (int j = 0; j < NJ; ++j) {
        int n = tid + (j << 8);
        float v = 0.0f;
        if (n < N) {
            float4 p = pb4[n];
            v = iou_fn(p.x, p.y, p.z, p.w, gx1, gy1, gx2, gy2);
            unsigned bits = __float_as_uint(v);
            if (bits) atomicAdd(&s_h[tid & (NH - 1)][bits >> 24], 1u);
        }
        myv[j] = v;
    }
    __syncthreads();

    hist_pick(s_h, s_wsum, s_sel, tid, lane, w, 0u, -1, 0u);
    const unsigned total = s_sel[2];
    unsigned thr_i = 0;
    if (total >= 13u) {
        unsigned pref = 0, mask = 0, need = total - 12u;  // asc rank of 13th-largest
        for (int lev = 0; lev < 4; ++lev) {
            int shift = 24 - 8 * lev;
            if (lev) {
                hist_zero(s_h, tid);
                __syncthreads();
#pragma unroll
                for (int j = 0; j < NJ; ++j) {
                    unsigned bits = __float_as_uint(myv[j]);
                    if (bits && (bits & mask) == pref)
                        atomicAdd(&s_h[tid & (NH - 1)][(bits >> shift) & 255u], 1u);
                }
                __syncthreads();
            }
            hist_pick(s_h, s_wsum, s_sel, tid, lane, w, need, -1, 0u);
            pref |= s_sel[0] << shift;
            mask |= 0xFFu << shift;
            need -= s_sel[1];
        }
        thr_i = pref;
    }
#pragma unroll
    for (int j = 0; j < NJ; ++j) {
        unsigned bits = __float_as_uint(myv[j]);
        if (bits > thr_i) {
            unsigned p = atomicAdd(&s_cnt, 1u);
            if (p < 16u) s_coll[p] = myv[j];              // <=12 strictly-greater items
        }
    }
    __syncthreads();
    if (tid == 0) {
        int cg = (int)s_cnt; if (cg > 13) cg = 13;
        for (int a = 1; a < cg; ++a) {
            float key = s_coll[a]; int bp = a - 1;
            while (bp >= 0 && s_coll[bp] < key) { s_coll[bp + 1] = s_coll[bp]; --bp; }
            s_coll[bp + 1] = key;
        }
        float ss = 0.0f;
        for (int a = 0; a < cg; ++a) ss += s_coll[a];     // descending-order sum
        if (total >= 13u) {
            float thr = __uint_as_float(thr_i);
            for (int a = cg; a < 13; ++a) ss += thr;
        }
        int KK = (int)ss;                                 // trunc == astype(int32)
        if (KK < 1) KK = 1;
        s_sel[3] = (unsigned)KK;
    }

    // ======== pass B: cost into registers; exact-INF excluded from hists ========
    hist_zero(s_h, tid);
    if (tid == 0) s_infcnt = 0;
    __syncthreads();
    const unsigned INFB = __float_as_uint(INF_COST);
    const float* tcol = tsc + (size_t)bm * N;
    const float* srow = pred_scores + (size_t)b * N * C;
    const unsigned char* vrow = valid + (size_t)b * N;
    const float4* pr4 = (const float4*)priors;
    unsigned cInf = 0;
    if (use_t) {
#pragma unroll
        for (int j = 0; j < NJ; ++j) {
            int n = tid + (j << 8);
            float c = 0.0f;
            if (n < N) {
                c = tcol[n];
                unsigned bits = __float_as_uint(c);
                if (bits == INFB) cInf++;
                else atomicAdd(&s_h[tid & (NH - 1)][bits >> 24], 1u);
            }
            myv[j] = c;                                   // OOR -> bits 0: never matches
        }
    } else {
#pragma unroll
        for (int j = 0; j < NJ; ++j) {
            int n = tid + (j << 8);
            float c = 0.0f;
            if (n < N) {
                if (vrow[n]) {
                    float logit = srow[(size_t)n * C + label];
                    float4 pr = pr4[n];
                    c = cost_fast(myv[j], logit, pr.x, pr.y,
                                  __builtin_amdgcn_rcpf(pr.z), gcx, gcy);
                } else c = INF_COST;
                unsigned bits = __float_as_uint(c);
                if (bits == INFB) cInf++;
                else atomicAdd(&s_h[tid & (NH - 1)][bits >> 24], 1u);
            }
            myv[j] = c;
        }
    }
#pragma unroll
    for (int d = 1; d < 64; d <<= 1) cInf += (unsigned)__shfl_xor((int)cInf, d);
    if (lane == 0 && cInf) atomicAdd(&s_infcnt, cInf);
    __syncthreads();
    const unsigned nInf = s_infcnt;
    const unsigned K = s_sel[3];

    unsigned pref = 0, mask = 0, need = K;
    for (int lev = 0; lev < 4; ++lev) {
        int shift = 24 - 8 * lev;
        if (lev) {
            hist_zero(s_h, tid);
            __syncthreads();
#pragma unroll
            for (int j = 0; j < NJ; ++j) {
                unsigned bits = __float_as_uint(myv[j]);
                if (bits && bits != INFB && (bits & mask) == pref)
                    atomicAdd(&s_h[tid & (NH - 1)][(bits >> shift) & 255u], 1u);
            }
            __syncthreads();
        }
        int infbin = ((INFB & mask) == pref) ? (int)((INFB >> shift) & 255u) : -1;
        hist_pick(s_h, s_wsum, s_sel, tid, lane, w, need, infbin, nInf);
        pref |= s_sel[0] << shift;
        mask |= 0xFFu << shift;
        need -= s_sel[1];
    }

    // ---- tie rank (ascending n) via ballots over register values ----
    for (int j = 0; j < NJ; ++j) {
        bool match = (__float_as_uint(myv[j]) == pref);
        unsigned long long bal = __ballot(match);
        if (lane == 0) s_wjc[w][j] = (unsigned)__popcll(bal);
    }
    __syncthreads();
    {
        const unsigned long long lt = (lane == 0) ? 0ull : (~0ull >> (64 - lane));
        unsigned cum = 0;
        for (int j = 0; j < NJ; ++j) {
            unsigned c0 = s_wjc[0][j], c1 = s_wjc[1][j], c2 = s_wjc[2][j], c3 = s_wjc[3][j];
            bool match = (__float_as_uint(myv[j]) == pref);
            unsigned long long bal = __ballot(match);
            unsigned before_w = (w > 0 ? c0 : 0u) + (w > 1 ? c1 : 0u) + (w > 2 ? c2 : 0u);
            unsigned rank_before = cum + before_w + (unsigned)__popcll(bal & lt);
            if (match && rank_before == need - 1u) s_sel[0] = (unsigned)(tid + (j << 8));
            cum += c0 + c1 + c2 + c3;
        }
    }
    __syncthreads();
    if (tid == 0) { cK[bm] = __uint_as_float(pref); nK[bm] = (int)s_sel[0]; }
}

// ---------- kernel 3: per-(b,n) row ----------
__global__ __launch_bounds__(256) void k_assign(
    const float* __restrict__ pred_bboxes,
    const float* __restrict__ pred_scores,
    const float* __restrict__ tsc,
    const float* __restrict__ priors,
    const int*   __restrict__ gt_labels,
    const float* __restrict__ gt_bboxes,
    const float* __restrict__ pad,
    const unsigned char* __restrict__ valid,
    const float* __restrict__ cK,
    const int*   __restrict__ nK,
    float* __restrict__ out,
    int use_t)
{
    __shared__ float s_box[M][4];
    __shared__ float s_gc[M][2];
    __shared__ float s_ck[M];
    __shared__ int   s_lab[M];
    __shared__ int   s_nk[M];
    __shared__ unsigned char s_gtv[M];

    const int cidx = blockIdx.x;
    const int b = cidx / 33;
    const int chunk = cidx % 33;
    const int n = chunk * 256 + threadIdx.x;

    if (threadIdx.x < M) {
        int m = threadIdx.x, gi = b * M + m;
        float4 g = ((const float4*)gt_bboxes)[gi];
        s_box[m][0] = g.x; s_box[m][1] = g.y; s_box[m][2] = g.z; s_box[m][3] = g.w;
        s_gc[m][0] = (g.x + g.z) * 0.5f;
        s_gc[m][1] = (g.y + g.w) * 0.5f;
        s_ck[m] = cK[gi];
        s_lab[m] = gt_labels[gi];
        s_nk[m] = nK[gi];
        s_gtv[m] = (pad[gi] > 0.0f) ? 1 : 0;
    }
    __syncthreads();
    if (n >= N) return;

    const size_t idx = (size_t)b * N + n;

    int count = 0, firstm = -1;
    float minc = INFINITY; int amin = 0;
    float firstiou = 0.0f, aminiou = 0.0f;

    if (use_t) {
        const float* tb = tsc + (size_t)b * M * N;
#pragma unroll 4
        for (int m = 0; m < M; m++) {
            float c = tb[(size_t)m * N + n];
            if (c < minc) { minc = c; amin = m; }
            float ckm = s_ck[m]; int nkm = s_nk[m];
            bool matched = s_gtv[m] && (c < ckm || (c == ckm && n <= nkm));
            if (matched) { count++; if (firstm < 0) firstm = m; }
        }
        int mstar = (count > 1) ? amin : firstm;
        float mi = 0.0f;
        if (mstar >= 0) {
            float4 p = ((const float4*)pred_bboxes)[idx];
            mi = iou_fn(p.x, p.y, p.z, p.w,
                        s_box[mstar][0], s_box[mstar][1], s_box[mstar][2], s_box[mstar][3]);
        }
        float* o_lab = out;
        float* o_w   = out + (size_t)B * N;
        float* o_box = out + (size_t)2 * B * N;
        float* o_met = out + (size_t)6 * B * N;
        o_w[idx] = 1.0f;
        if (mstar >= 0) {
            o_lab[idx] = (float)s_lab[mstar];
            o_box[idx * 4 + 0] = s_box[mstar][0];
            o_box[idx * 4 + 1] = s_box[mstar][1];
            o_box[idx * 4 + 2] = s_box[mstar][2];
            o_box[idx * 4 + 3] = s_box[mstar][3];
            o_met[idx] = mi;
        } else {
            o_lab[idx] = (float)C;
            o_box[idx * 4 + 0] = 0.0f;
            o_box[idx * 4 + 1] = 0.0f;
            o_box[idx * 4 + 2] = 0.0f;
            o_box[idx * 4 + 3] = 0.0f;
            o_met[idx] = 0.0f;
        }
        return;
    }

    // -------- fallback (use_t == 0) --------
    const float4 p = ((const float4*)pred_bboxes)[idx];
    const float4 pr = ((const float4*)priors)[n];
    const float rst = __builtin_amdgcn_rcpf(pr.z);
    const int vn = valid[idx];
    const float* scores = pred_scores + idx * C;

    for (int m = 0; m < M; m++) {
        float iou = iou_fn(p.x, p.y, p.z, p.w,
                           s_box[m][0], s_box[m][1], s_box[m][2], s_box[m][3]);
        float c;
        if (vn) {
            float logit = scores[s_lab[m]];
            c = cost_fast(iou, logit, pr.x, pr.y, rst, s_gc[m][0], s_gc[m][1]);
        } else {
            c = INF_COST;
        }
        if (c < minc) { minc = c; amin = m; aminiou = iou; }
        float ckm = s_ck[m]; int nkm = s_nk[m];
        bool matched = s_gtv[m] && (c < ckm || (c == ckm && n <= nkm));
        if (matched) { count++; if (firstm < 0) { firstm = m; firstiou = iou; } }
    }

    int mstar; float mi;
    if (count > 1)       { mstar = amin;   mi = aminiou; }
    else if (count == 1) { mstar = firstm; mi = firstiou; }
    else                 { mstar = -1;     mi = 0.0f; }

    float* o_lab = out;
    float* o_w   = out + (size_t)B * N;
    float* o_box = out + (size_t)2 * B * N;
    float* o_met = out + (size_t)6 * B * N;
    o_w[idx] = 1.0f;
    if (mstar >= 0) {
        o_lab[idx] = (float)s_lab[mstar];
        o_box[idx * 4 + 0] = s_box[mstar][0];
        o_box[idx * 4 + 1] = s_box[mstar][1];
        o_box[idx * 4 + 2] = s_box[mstar][2];
        o_box[idx * 4 + 3] = s_box[mstar][3];
        o_met[idx] = mi;
    } else {
        o_lab[idx] = (float)C;
        o_box[idx * 4 + 0] = 0.0f;
        o_box[idx * 4 + 1] = 0.0f;
        o_box[idx * 4 + 2] = 0.0f;
        o_box[idx * 4 + 3] = 0.0f;
        o_met[idx] = 0.0f;
    }
}

extern "C" void kernel_launch(void* const* d_in, const int* in_sizes, int n_in,
                              void* d_out, int out_size, void* d_ws, size_t ws_size,
                              hipStream_t stream) {
    const float* pred_bboxes = (const float*)d_in[0];
    const float* pred_scores = (const float*)d_in[1];
    const float* priors      = (const float*)d_in[2];
    const int*   gt_labels   = (const int*)d_in[3];
    const float* gt_bboxes   = (const float*)d_in[4];
    const float* pad         = (const float*)d_in[5];
    float* out = (float*)d_out;

    const size_t t_bytes = (size_t)B * M * N * sizeof(float);
    const size_t need = t_bytes + (size_t)B * N + (size_t)B * M * 8;
    const int use_t = (ws_size >= need) ? 1 : 0;

    unsigned char* ws = (unsigned char*)d_ws;
    float* tsc; unsigned char* valid; float* cKp; int* nKp;
    if (use_t) {
        tsc   = (float*)ws;
        valid = ws + t_bytes;
        cKp   = (float*)(ws + t_bytes + (size_t)B * N);
        nKp   = (int*)  (ws + t_bytes + (size_t)B * N + (size_t)B * M * 4);
    } else {
        tsc   = (float*)ws;   // never dereferenced
        valid = ws;
        cKp   = (float*)(ws + (size_t)B * N);
        nKp   = (int*)  (ws + (size_t)B * N + (size_t)B * M * 4);
    }

    k_valid<<<(B * N + 255) / 256, 256, 0, stream>>>(priors, gt_bboxes, pad, valid);
    if (use_t)
        k_cost<<<B * 132, 256, 0, stream>>>(pred_scores, gt_labels, pred_bboxes, priors,
                                            gt_bboxes, valid, tsc);
    k_select<<<B * M, 256, 0, stream>>>(pred_bboxes, pred_scores, tsc, priors, gt_labels,
                                        gt_bboxes, pad, valid, cKp, nKp, use_t);
    k_assign<<<33 * B, 256, 0, stream>>>(pred_bboxes, pred_scores, tsc, priors, gt_labels,
                                         gt_bboxes, pad, valid, cKp, nKp, out, use_t);
}

// Round 13
// 175.301 us; speedup vs baseline: 1.3866x; 1.0141x over previous
//
#include <hip/hip_runtime.h>
#include <hip/hip_bf16.h>
#include <math.h>

#define B 32
#define N 8400
#define M 60
#define C 80
#define INF_COST 1e8f
#define NJ 33   // ceil(N/256)

typedef unsigned long long u64;

// ---------- iou: bit-exact IEEE, identical codegen in all kernels ----------
__device__ __forceinline__ float iou_fn(
    float px1, float py1, float px2, float py2,
    float gx1, float gy1, float gx2, float gy2)
{
#pragma clang fp contract(off)
    float ltx = fmaxf(px1, gx1), lty = fmaxf(py1, gy1);
    float rbx = fminf(px2, gx2), rby = fminf(py2, gy2);
    float wx = fmaxf(rbx - ltx, 0.0f), wy = fmaxf(rby - lty, 0.0f);
    float inter = wx * wy;
    float a1 = (px2 - px1) * (py2 - py1);
    float a2 = (gx2 - gx1) * (gy2 - gy1);
    float uni = fmaxf(a1 + a2 - inter, 1e-6f);
    return inter / uni;
}

// ---------- cost: fast HW transcendentals; contract(off) pins identical bits
// in k_sel and k_assign (two producers now) ----------
__device__ __forceinline__ float cost_fast(
    float iou, float logit,
    float pcx, float pcy, float rstride,   // rstride = 1/stride (exact: pow2)
    float gcx, float gcy)
{
#pragma clang fp contract(off)
    const float LOG2_10 = 3.3219280948873623f;
    const float LOG2_E  = 1.4426950408889634f;
    const float LN_2    = 0.6931471805599453f;
    float dx = pcx - gcx, dy = pcy - gcy;
    float dist = __builtin_amdgcn_sqrtf(dx * dx + dy * dy) * rstride;
    float soft = __builtin_amdgcn_exp2f((dist - 3.0f) * LOG2_10);
    float iouc = __builtin_amdgcn_logf(iou + 1e-7f) * (-3.0f * LN_2);
    float e    = __builtin_amdgcn_exp2f(-logit * LOG2_E);
    float sig  = __builtin_amdgcn_rcpf(1.0f + e);
    float t    = __builtin_amdgcn_exp2f(-fabsf(logit) * LOG2_E);
    float sp   = __builtin_amdgcn_logf(1.0f + t) * LN_2;
    float bce  = fmaxf(logit, 0.0f) - logit * iou + sp;
    float scale = iou - sig;
    float cls  = bce * scale * scale;
    return (cls + iouc) + soft;
}

// ---------- kernel 1: valid_mask[b,n] ----------
__global__ __launch_bounds__(256) void k_valid(
    const float* __restrict__ priors,
    const float* __restrict__ gt_bboxes,
    const float* __restrict__ pad,
    unsigned char* __restrict__ valid)
{
    int idx = blockIdx.x * 256 + threadIdx.x;
    if (idx >= B * N) return;
    int b = idx / N, n = idx % N;
    float px = priors[n * 4 + 0];
    float py = priors[n * 4 + 1];
    const float* g = gt_bboxes + (size_t)b * M * 4;
    const float* pf = pad + (size_t)b * M;
    unsigned char v = 0;
    for (int m = 0; m < M; m++) {
        float x1 = g[m * 4 + 0], y1 = g[m * 4 + 1];
        float x2 = g[m * 4 + 2], y2 = g[m * 4 + 3];
        float mn = fminf(fminf(px - x1, py - y1), fminf(x2 - px, y2 - py));
        if (mn > 0.0f && pf[m] > 0.0f) { v = 1; break; }
    }
    valid[idx] = v;
}

// ---------- kernel 2: per-column select via threshold prefilter ----------
// grid 1920; b-grouped XCD swizzle: XCD x handles b in [4x, 4x+4) -> score
// region (2.7 MB/b) stays L2-resident across its 60 column-gathers.
__global__ __launch_bounds__(256) void k_sel(
    const float* __restrict__ pred_bboxes,
    const float* __restrict__ pred_scores,
    const float* __restrict__ priors,
    const int*   __restrict__ gt_labels,
    const float* __restrict__ gt_bboxes,
    const float* __restrict__ pad,
    const unsigned char* __restrict__ valid,
    float* __restrict__ cK, int* __restrict__ nK)
{
    __shared__ u64      s_pair[256];     // reused: cost-min keys, then iou-max keys
    __shared__ u64      s_tkey[2];
    __shared__ float    s_candv[512];    // candidates: provably <= 396
    __shared__ int      s_candn[512];
    __shared__ float    s_slot[13];
    __shared__ unsigned s_cnt;
    __shared__ unsigned s_K;
    __shared__ u64      s_ans;

    const int i = blockIdx.x;
    const int xcd = i & 7, k = i >> 3;
    const int b = xcd * 4 + (k / 60);
    const int m = k % 60;
    const int bm = b * M + m;
    if (pad[bm] == 0.0f) return;         // padded GT: cK/nK never consumed

    const int tid = threadIdx.x;

    const float4 g = ((const float4*)gt_bboxes)[bm];
    const float gx1 = g.x, gy1 = g.y, gx2 = g.z, gy2 = g.w;
    const float gcx = (gx1 + gx2) * 0.5f, gcy = (gy1 + gy2) * 0.5f;
    const int label = gt_labels[bm];
    const float4* pb4 = ((const float4*)pred_bboxes) + (size_t)b * N;
    const float* srow = pred_scores + (size_t)b * N * C;
    const unsigned char* vrow = valid + (size_t)b * N;
    const float4* pr4 = (const float4*)priors;

    float myi[NJ], myc[NJ];
    u64 minc = ~0ull, maxi = ~0ull;      // lex-min keys

    // ---- single fused scan: iou (compute) + cost (compute, gathered logit) ----
#pragma unroll
    for (int j = 0; j < NJ; ++j) {
        int n = tid + (j << 8);
        float v = 0.0f, c = 0.0f;
        if (n < N) {
            float4 p = pb4[n];
            v = iou_fn(p.x, p.y, p.z, p.w, gx1, gy1, gx2, gy2);
            if (vrow[n]) {
                float4 pr = pr4[n];
                c = cost_fast(v, srow[(size_t)n * C + label], pr.x, pr.y,
                              __builtin_amdgcn_rcpf(pr.z), gcx, gcy);
            } else c = INF_COST;
            u64 ck = ((u64)__float_as_uint(c) << 32) | (unsigned)n;   // cost asc, n asc
            if (ck < minc) minc = ck;
            u64 ik = ((u64)(0xFFFFFFFFu - __float_as_uint(v)) << 32) | (unsigned)n; // iou desc, n asc
            if (ik < maxi) maxi = ik;
        }
        myi[j] = v; myc[j] = c;
    }

    // ---- threshold 1: 13th-smallest cost key among 256 thread minima ----
    s_pair[tid] = minc;
    __syncthreads();
    {
        unsigned r = 0;
        for (int t = 0; t < 256; ++t) r += (s_pair[t] < minc) ? 1u : 0u;
        if (r == 12u) s_tkey[0] = minc;          // keys unique: exactly one writer
    }
    __syncthreads();

    // ---- threshold 2: 13th-largest iou key among 256 thread maxima ----
    s_pair[tid] = maxi;
    if (tid == 0) s_cnt = 0;
    __syncthreads();
    {
        unsigned r = 0;
        for (int t = 0; t < 256; ++t) r += (s_pair[t] < maxi) ? 1u : 0u;
        if (r == 12u) s_tkey[1] = maxi;
    }
    __syncthreads();
    const u64 tc = s_tkey[0];
    const float ti_v = __uint_as_float(0xFFFFFFFFu - (unsigned)(s_tkey[1] >> 32));

    // ---- iou candidates: value strictly > ti_v (<= 12 threads can contribute) ----
#pragma unroll
    for (int j = 0; j < NJ; ++j) {
        int n = tid + (j << 8);
        if (n < N && myi[j] > ti_v) {
            unsigned p = atomicAdd(&s_cnt, 1u);
            s_candv[p] = myi[j]; s_candn[p] = n;
        }
    }
    __syncthreads();
    const unsigned ng = s_cnt;                   // <= 396

    // parallel rank (value desc, n asc); ranks 0..12 -> slots
    for (unsigned ii = tid; ii < ng; ii += 256) {
        float v = s_candv[ii]; int nn = s_candn[ii];
        unsigned r = 0;
        for (unsigned t = 0; t < ng; ++t) {
            float u = s_candv[t];
            r += (u > v || (u == v && s_candn[t] < nn)) ? 1u : 0u;
        }
        if (r < 13u) s_slot[r] = v;
    }
    __syncthreads();
    if (tid == 0) {
        int avail = (ng < 13u) ? (int)ng : 13;
        float ss = 0.0f;
        for (int a = 0; a < avail; ++a) ss += s_slot[a];      // descending order
        if (ti_v > 0.0f)                                      // fill ties; zeros are +0.0 no-ops
            for (int a = avail; a < 13; ++a) ss += ti_v;
        int K = (int)ss;                                      // trunc == astype(int32)
        if (K < 1) K = 1;
        s_K = (unsigned)K;
        s_cnt = 0;
    }
    __syncthreads();

    // ---- cost candidates: key strictly < tc (<= 12 threads can contribute) ----
#pragma unroll
    for (int j = 0; j < NJ; ++j) {
        int n = tid + (j << 8);
        if (n < N) {
            u64 ck = ((u64)__float_as_uint(myc[j]) << 32) | (unsigned)n;
            if (ck < tc) {
                unsigned p = atomicAdd(&s_cnt, 1u);
                s_candv[p] = myc[j]; s_candn[p] = n;
            }
        }
    }
    __syncthreads();
    const unsigned nc = s_cnt;                   // >= 12, <= 396
    const unsigned K = s_K;

    if (K <= nc) {
        for (unsigned ii = tid; ii < nc; ii += 256) {
            float c = s_candv[ii]; int nn = s_candn[ii];
            unsigned r = 0;
            for (unsigned t = 0; t < nc; ++t) {
                float u = s_candv[t];
                r += (u < c || (u == c && s_candn[t] < nn)) ? 1u : 0u;
            }
            if (r == K - 1u) s_ans = ((u64)__float_as_uint(c) << 32) | (unsigned)nn;
        }
    } else {                                     // K == nc + 1: threshold pair itself
        if (tid == 0) s_ans = tc;
    }
    __syncthreads();
    if (tid == 0) {
        u64 a = s_ans;
        cK[bm] = __uint_as_float((unsigned)(a >> 32));
        nK[bm] = (int)(a & 0xFFFFFFFFu);
    }
}

// ---------- kernel 3: per-(b,n) row; recomputes cost (bit-identical to k_sel) ----------
__global__ __launch_bounds__(256) void k_assign(
    const float* __restrict__ pred_bboxes,
    const float* __restrict__ pred_scores,
    const float* __restrict__ priors,
    const int*   __restrict__ gt_labels,
    const float* __restrict__ gt_bboxes,
    const float* __restrict__ pad,
    const unsigned char* __restrict__ valid,
    const float* __restrict__ cK,
    const int*   __restrict__ nK,
    float* __restrict__ out)
{
    __shared__ float s_box[M][4];
    __shared__ float s_gc[M][2];
    __shared__ float s_ck[M];
    __shared__ int   s_lab[M];
    __shared__ int   s_nk[M];
    __shared__ unsigned char s_gtv[M];

    const int cidx = blockIdx.x;
    const int b = cidx / 33;
    const int chunk = cidx % 33;
    const int n = chunk * 256 + threadIdx.x;

    if (threadIdx.x < M) {
        int m = threadIdx.x, gi = b * M + m;
        float4 g = ((const float4*)gt_bboxes)[gi];
        s_box[m][0] = g.x; s_box[m][1] = g.y; s_box[m][2] = g.z; s_box[m][3] = g.w;
        s_gc[m][0] = (g.x + g.z) * 0.5f;
        s_gc[m][1] = (g.y + g.w) * 0.5f;
        s_ck[m] = cK[gi];
        s_lab[m] = gt_labels[gi];
        s_nk[m] = nK[gi];
        s_gtv[m] = (pad[gi] > 0.0f) ? 1 : 0;
    }
    __syncthreads();
    if (n >= N) return;

    const size_t idx = (size_t)b * N + n;
    const float4 p = ((const float4*)pred_bboxes)[idx];
    const float4 pr = ((const float4*)priors)[n];
    const float rst = __builtin_amdgcn_rcpf(pr.z);
    const int vn = valid[idx];
    const float* scores = pred_scores + idx * C;

    int count = 0, firstm = -1;
    float minc = INFINITY; int amin = 0;
    float firstiou = 0.0f, aminiou = 0.0f;

#pragma unroll 4
    for (int m = 0; m < M; m++) {
        float iou = iou_fn(p.x, p.y, p.z, p.w,
                           s_box[m][0], s_box[m][1], s_box[m][2], s_box[m][3]);
        float c;
        if (vn) {
            float logit = scores[s_lab[m]];
            c = cost_fast(iou, logit, pr.x, pr.y, rst, s_gc[m][0], s_gc[m][1]);
        } else {
            c = INF_COST;
        }
        if (c < minc) { minc = c; amin = m; aminiou = iou; }  // first-min, like jnp.argmin
        float ckm = s_ck[m]; int nkm = s_nk[m];
        bool matched = s_gtv[m] && (c < ckm || (c == ckm && n <= nkm));
        if (matched) { count++; if (firstm < 0) { firstm = m; firstiou = iou; } }
    }

    int mstar; float mi;
    if (count > 1)       { mstar = amin;   mi = aminiou; }
    else if (count == 1) { mstar = firstm; mi = firstiou; }
    else                 { mstar = -1;     mi = 0.0f; }

    float* o_lab = out;
    float* o_w   = out + (size_t)B * N;
    float* o_box = out + (size_t)2 * B * N;
    float* o_met = out + (size_t)6 * B * N;
    o_w[idx] = 1.0f;
    if (mstar >= 0) {
        o_lab[idx] = (float)s_lab[mstar];
        o_box[idx * 4 + 0] = s_box[mstar][0];
        o_box[idx * 4 + 1] = s_box[mstar][1];
        o_box[idx * 4 + 2] = s_box[mstar][2];
        o_box[idx * 4 + 3] = s_box[mstar][3];
        o_met[idx] = mi;
    } else {
        o_lab[idx] = (float)C;
        o_box[idx * 4 + 0] = 0.0f;
        o_box[idx * 4 + 1] = 0.0f;
        o_box[idx * 4 + 2] = 0.0f;
        o_box[idx * 4 + 3] = 0.0f;
        o_met[idx] = 0.0f;
    }
}

extern "C" void kernel_launch(void* const* d_in, const int* in_sizes, int n_in,
                              void* d_out, int out_size, void* d_ws, size_t ws_size,
                              hipStream_t stream) {
    const float* pred_bboxes = (const float*)d_in[0];
    const float* pred_scores = (const float*)d_in[1];
    const float* priors      = (const float*)d_in[2];
    const int*   gt_labels   = (const int*)d_in[3];
    const float* gt_bboxes   = (const float*)d_in[4];
    const float* pad         = (const float*)d_in[5];
    float* out = (float*)d_out;

    unsigned char* ws = (unsigned char*)d_ws;
    unsigned char* valid = ws;                                    // B*N bytes
    float* cKp = (float*)(ws + (size_t)B * N);                    // B*M floats
    int*   nKp = (int*)  (ws + (size_t)B * N + (size_t)B * M * 4);// B*M ints

    k_valid<<<(B * N + 255) / 256, 256, 0, stream>>>(priors, gt_bboxes, pad, valid);
    k_sel  <<<B * M, 256, 0, stream>>>(pred_bboxes, pred_scores, priors, gt_labels,
                                       gt_bboxes, pad, valid, cKp, nKp);
    k_assign<<<33 * B, 256, 0, stream>>>(pred_bboxes, pred_scores, priors, gt_labels,
                                         gt_bboxes, pad, valid, cKp, nKp, out);
}